// Round 21
// baseline (123.643 us; speedup 1.0000x reference)
//
#include <hip/hip_runtime.h>

// BeamDelay2AntFreq: (256,32,8,4,2,48) complex -> ifft4(V) -> ifft8(H) -> fft48(t),
// fftshifts folded into (-1)^{h+v+f}; ortho norm 1/sqrt(1536).
// OUTPUT: interleaved bf16 pairs IMAG FIRST: dword = im | (re<<16), (b,c,row,f) order.
// R21 = R19 + phases A/B fused in registers: S never touches LDS; the quad
// exchange uses DPP quad_perm broadcasts (VALU) instead of ds ops. LDS
// wave-insts/block halve (960 -> 480); LDS pipe was the R19 bottleneck.

namespace {

constexpr int RP = 49;       // T row stride (floats); span 48 < 49 => rows wave-private
constexpr float NORM = 0.02551551815399144f;  // 1/sqrt(1536)
constexpr float R2  = 0.70710678f;            // 1/sqrt(2)
constexpr float C30 = 0.86602540f;            // cos(30)

constexpr float COS48[48] = {
  1.0f,        0.99144486f,  0.96592583f,  0.92387953f,  0.86602540f,  0.79335334f,
  0.70710678f, 0.60876143f,  0.5f,         0.38268343f,  0.25881905f,  0.13052619f,
  0.0f,       -0.13052619f, -0.25881905f, -0.38268343f, -0.5f,        -0.60876143f,
 -0.70710678f,-0.79335334f, -0.86602540f, -0.92387953f, -0.96592583f, -0.99144486f,
 -1.0f,       -0.99144486f, -0.96592583f, -0.92387953f, -0.86602540f, -0.79335334f,
 -0.70710678f,-0.60876143f, -0.5f,        -0.38268343f, -0.25881905f, -0.13052619f,
  0.0f,        0.13052619f,  0.25881905f,  0.38268343f,  0.5f,         0.60876143f,
  0.70710678f, 0.79335334f,  0.86602540f,  0.92387953f,  0.96592583f,  0.99144486f
};
constexpr float SIN48[48] = {
  0.0f,        0.13052619f,  0.25881905f,  0.38268343f,  0.5f,         0.60876143f,
  0.70710678f, 0.79335334f,  0.86602540f,  0.92387953f,  0.96592583f,  0.99144486f,
  1.0f,        0.99144486f,  0.96592583f,  0.92387953f,  0.86602540f,  0.79335334f,
  0.70710678f, 0.60876143f,  0.5f,         0.38268343f,  0.25881905f,  0.13052619f,
  0.0f,       -0.13052619f, -0.25881905f, -0.38268343f, -0.5f,        -0.60876143f,
 -0.70710678f,-0.79335334f, -0.86602540f, -0.92387953f, -0.96592583f, -0.99144486f,
 -1.0f,       -0.99144486f, -0.96592583f, -0.92387953f, -0.86602540f, -0.79335334f,
 -0.70710678f,-0.60876143f, -0.5f,        -0.38268343f, -0.25881905f, -0.13052619f
};

__device__ __forceinline__ unsigned bf16_rne(float x) {
  unsigned u = __float_as_uint(x);
  u += 0x7FFFu + ((u >> 16) & 1u);
  return u >> 16;
}

// Broadcast lane B of each 4-lane quad across the quad (pure VALU via DPP).
template<int B>
__device__ __forceinline__ float quad_bcast(float v) {
  constexpr int ctrl = B * 0x55;   // quad_perm [B,B,B,B]
  return __int_as_float(
      __builtin_amdgcn_mov_dpp(__float_as_int(v), ctrl, 0xF, 0xF, true));
}

__global__ __launch_bounds__(256, 6)
void bd2af_kernel(const float* __restrict__ xr, const float* __restrict__ xi,
                  unsigned* __restrict__ out, int nbc) {
  __shared__ float Tr[64 * RP], Ti[64 * RP];   // X->T1->Y overlay

  const int tid = threadIdx.x;
  const int bc = blockIdx.x;
  if (bc >= nbc) return;

  const float* gxr = xr + (size_t)bc * 3072;
  const float* gxi = xi + (size_t)bc * 3072;

  // ---- V phase: global -> reg, 4-pt inverse FFT (kernel i^{V v'}), write T1 ----
  {
    const int hq = tid >> 5;           // 0..7
    const int p  = (tid >> 4) & 1;
    const int tc = tid & 15;
    const int t0 = 3 * tc;
    const int rowb = hq * 8 + p;       // row = rowb + 2V
#pragma unroll
    for (int k = 0; k < 3; ++k) {
      const int tt = t0 + k;
      const float x0r = gxr[(rowb + 0) * 48 + tt], x0i = gxi[(rowb + 0) * 48 + tt];
      const float x1r = gxr[(rowb + 2) * 48 + tt], x1i = gxi[(rowb + 2) * 48 + tt];
      const float x2r = gxr[(rowb + 4) * 48 + tt], x2i = gxi[(rowb + 4) * 48 + tt];
      const float x3r = gxr[(rowb + 6) * 48 + tt], x3i = gxi[(rowb + 6) * 48 + tt];
      const float e0r = x0r + x2r, e0i = x0i + x2i;
      const float e1r = x0r - x2r, e1i = x0i - x2i;
      const float o0r = x1r + x3r, o0i = x1i + x3i;
      const float o1r = x1r - x3r, o1i = x1i - x3i;
      Tr[(rowb + 0) * RP + tt] = e0r + o0r;  Ti[(rowb + 0) * RP + tt] = e0i + o0i;
      Tr[(rowb + 2) * RP + tt] = e1r - o1i;  Ti[(rowb + 2) * RP + tt] = e1i + o1r;  // +i*o1
      Tr[(rowb + 4) * RP + tt] = e0r - o0r;  Ti[(rowb + 4) * RP + tt] = e0i - o0i;
      Tr[(rowb + 6) * RP + tt] = e1r + o1i;  Ti[(rowb + 6) * RP + tt] = e1i - o1r;  // -i*o1
    }
  }
  __syncthreads();

  // ---- H phase (128 threads): 8-pt inverse FFT in-place, with (-1)^{h'+v'} ----
  if (tid < 128) {
    const int vq = tid >> 5;           // 0..3
    const int p  = (tid >> 4) & 1;
    const int tc = tid & 15;
    const int t0 = 3 * tc;
    const int rowb = 2 * vq + p;       // row = rowb + 8H
    const float sgnE = (vq & 1) ? -1.f : 1.f;   // (-1)^{h'+vq}, h' even
    const float sgnO = -sgnE;                   // h' odd
#pragma unroll
    for (int k = 0; k < 3; ++k) {
      const int tt = t0 + k;
      const float t0r = Tr[(rowb +  0) * RP + tt], t0i = Ti[(rowb +  0) * RP + tt];
      const float t1r = Tr[(rowb +  8) * RP + tt], t1i = Ti[(rowb +  8) * RP + tt];
      const float t2r = Tr[(rowb + 16) * RP + tt], t2i = Ti[(rowb + 16) * RP + tt];
      const float t3r = Tr[(rowb + 24) * RP + tt], t3i = Ti[(rowb + 24) * RP + tt];
      const float t4r = Tr[(rowb + 32) * RP + tt], t4i = Ti[(rowb + 32) * RP + tt];
      const float t5r = Tr[(rowb + 40) * RP + tt], t5i = Ti[(rowb + 40) * RP + tt];
      const float t6r = Tr[(rowb + 48) * RP + tt], t6i = Ti[(rowb + 48) * RP + tt];
      const float t7r = Tr[(rowb + 56) * RP + tt], t7i = Ti[(rowb + 56) * RP + tt];
      const float e0r = t0r + t4r, e0i = t0i + t4i, e1r = t0r - t4r, e1i = t0i - t4i;
      const float o0r = t2r + t6r, o0i = t2i + t6i, o1r = t2r - t6r, o1i = t2i - t6i;
      const float E0r = e0r + o0r, E0i = e0i + o0i;
      const float E2r = e0r - o0r, E2i = e0i - o0i;
      const float E1r = e1r - o1i, E1i = e1i + o1r;   // e1 + i o1
      const float E3r = e1r + o1i, E3i = e1i - o1r;   // e1 - i o1
      const float f0r = t1r + t5r, f0i = t1i + t5i, f1r = t1r - t5r, f1i = t1i - t5i;
      const float g0r = t3r + t7r, g0i = t3i + t7i, g1r = t3r - t7r, g1i = t3i - t7i;
      const float O0r = f0r + g0r, O0i = f0i + g0i;
      const float O2r = f0r - g0r, O2i = f0i - g0i;
      const float O1r = f1r - g1i, O1i = f1i + g1r;
      const float O3r = f1r + g1i, O3i = f1i - g1r;
      const float W1r = R2 * (O1r - O1i), W1i = R2 * (O1r + O1i);
      const float W3r = R2 * (-O3r - O3i), W3i = R2 * (O3r - O3i);
      Tr[(rowb +  0) * RP + tt] = sgnE * (E0r + O0r);  Ti[(rowb +  0) * RP + tt] = sgnE * (E0i + O0i);
      Tr[(rowb + 32) * RP + tt] = sgnE * (E0r - O0r);  Ti[(rowb + 32) * RP + tt] = sgnE * (E0i - O0i);
      Tr[(rowb + 16) * RP + tt] = sgnE * (E2r - O2i);  Ti[(rowb + 16) * RP + tt] = sgnE * (E2i + O2r);
      Tr[(rowb + 48) * RP + tt] = sgnE * (E2r + O2i);  Ti[(rowb + 48) * RP + tt] = sgnE * (E2i - O2r);
      Tr[(rowb +  8) * RP + tt] = sgnO * (E1r + W1r);  Ti[(rowb +  8) * RP + tt] = sgnO * (E1i + W1i);
      Tr[(rowb + 40) * RP + tt] = sgnO * (E1r - W1r);  Ti[(rowb + 40) * RP + tt] = sgnO * (E1i - W1i);
      Tr[(rowb + 24) * RP + tt] = sgnO * (E3r + W3r);  Ti[(rowb + 24) * RP + tt] = sgnO * (E3i + W3i);
      Tr[(rowb + 56) * RP + tt] = sgnO * (E3r - W3r);  Ti[(rowb + 56) * RP + tt] = sgnO * (E3i - W3i);
    }
  }
  __syncthreads();

  // ---- Fused A+B: radix-12 DFT in registers, quad DPP exchange, combine, store ----
  {
    const int r = tid >> 2;
    const int b = tid & 3;      // doubles as c (output freq chunk) in the B step
    // Phase A: S[b][j] = sum_a z[4a+b] W12^{aj}  (z from LDS, stride-4 reads)
    float zr[12], zi[12];
#pragma unroll
    for (int a = 0; a < 12; ++a) {
      zr[a] = Tr[r * RP + 4 * a + b];
      zi[a] = Ti[r * RP + 4 * a + b];
    }
    float h0r[3], h0i[3], h1r[3], h1i[3], h2r[3], h2i[3], h3r[3], h3i[3];
#pragma unroll
    for (int a2 = 0; a2 < 3; ++a2) {
      const float e0r = zr[a2] + zr[a2 + 6], e0i = zi[a2] + zi[a2 + 6];
      const float e1r = zr[a2] - zr[a2 + 6], e1i = zi[a2] - zi[a2 + 6];
      const float o0r = zr[a2 + 3] + zr[a2 + 9], o0i = zi[a2 + 3] + zi[a2 + 9];
      const float o1r = zr[a2 + 3] - zr[a2 + 9], o1i = zi[a2 + 3] - zi[a2 + 9];
      h0r[a2] = e0r + o0r;  h0i[a2] = e0i + o0i;
      h2r[a2] = e0r - o0r;  h2i[a2] = e0i - o0i;
      h1r[a2] = e1r + o1i;  h1i[a2] = e1i - o1r;   // e1 - i o1 (forward)
      h3r[a2] = e1r - o1i;  h3i[a2] = e1i + o1r;   // e1 + i o1
    }
    {
      float a, bb;
      a = h1r[1]; bb = h1i[1];
      h1r[1] = C30 * a + 0.5f * bb;  h1i[1] = C30 * bb - 0.5f * a;
      a = h2r[1]; bb = h2i[1];
      h2r[1] = 0.5f * a + C30 * bb;  h2i[1] = 0.5f * bb - C30 * a;
      a = h3r[1]; bb = h3i[1];
      h3r[1] = bb;                   h3i[1] = -a;
      a = h1r[2]; bb = h1i[2];
      h1r[2] = 0.5f * a + C30 * bb;  h1i[2] = 0.5f * bb - C30 * a;
      a = h2r[2]; bb = h2i[2];
      h2r[2] = -0.5f * a + C30 * bb; h2i[2] = -0.5f * bb - C30 * a;
      h3r[2] = -h3r[2];              h3i[2] = -h3i[2];
    }
    float s_r[12], s_i[12];
#define DFT3(J1, HR, HI)                                                    \
    {                                                                       \
      const float tr_ = HR[1] + HR[2], ti_ = HI[1] + HI[2];                 \
      const float dr_ = HR[1] - HR[2], di_ = HI[1] - HI[2];                 \
      const float mr_ = HR[0] - 0.5f * tr_, mi_ = HI[0] - 0.5f * ti_;       \
      const float wr_ = C30 * dr_, wi_ = C30 * di_;                         \
      s_r[J1]     = HR[0] + tr_;  s_i[J1]     = HI[0] + ti_;                \
      s_r[J1 + 4] = mr_ + wi_;    s_i[J1 + 4] = mi_ - wr_;                  \
      s_r[J1 + 8] = mr_ - wi_;    s_i[J1 + 8] = mi_ + wr_;                  \
    }
    DFT3(0, h0r, h0i)
    DFT3(1, h1r, h1i)
    DFT3(2, h2r, h2i)
    DFT3(3, h3r, h3i)
#undef DFT3

    // Phase B (register-only): out[12c+j] = sum_b rot_c^b * S[b][j] * W48^{bj}
    // rot_c = (-i)^c. S[b][j] gathered from quad lane b via DPP broadcast.
    const float a1r = (b == 0) ? 1.f : ((b == 2) ? -1.f : 0.f);
    const float a1i = (b == 1) ? -1.f : ((b == 3) ? 1.f : 0.f);
    const float s2  = (b & 1) ? -1.f : 1.f;
    unsigned pk[12];
#pragma unroll
    for (int j = 0; j < 12; ++j) {
      const float S0r = quad_bcast<0>(s_r[j]), S0i = quad_bcast<0>(s_i[j]);
      const float S1r = quad_bcast<1>(s_r[j]), S1i = quad_bcast<1>(s_i[j]);
      const float S2r = quad_bcast<2>(s_r[j]), S2i = quad_bcast<2>(s_i[j]);
      const float S3r = quad_bcast<3>(s_r[j]), S3i = quad_bcast<3>(s_i[j]);
      float orr = S0r, oii = S0i;
      {  // b' = 1: (-i)^c * S1 * W48^j
        const float wr = COS48[j], wi = -SIN48[j];
        const float tr = S1r * wr - S1i * wi, ti = S1r * wi + S1i * wr;
        orr += a1r * tr - a1i * ti;
        oii += a1r * ti + a1i * tr;
      }
      {  // b' = 2: (-1)^c * S2 * W48^{2j}
        const float wr = COS48[(2 * j) % 48], wi = -SIN48[(2 * j) % 48];
        const float tr = S2r * wr - S2i * wi, ti = S2r * wi + S2i * wr;
        orr += s2 * tr;
        oii += s2 * ti;
      }
      {  // b' = 3: (i)^c * S3 * W48^{3j}
        const float wr = COS48[(3 * j) % 48], wi = -SIN48[(3 * j) % 48];
        const float tr = S3r * wr - S3i * wi, ti = S3r * wi + S3i * wr;
        orr += a1r * tr + a1i * ti;
        oii += a1r * ti - a1i * tr;
      }
      const float s = (j & 1) ? -NORM : NORM;   // (-1)^f = (-1)^j since f = 12c+j
      pk[j] = bf16_rne(oii * s) | (bf16_rne(orr * s) << 16);
    }
    unsigned* og = out + (size_t)bc * 3072 + r * 48 + b * 12;
    *reinterpret_cast<uint4*>(og)     = make_uint4(pk[0], pk[1], pk[2],  pk[3]);
    *reinterpret_cast<uint4*>(og + 4) = make_uint4(pk[4], pk[5], pk[6],  pk[7]);
    *reinterpret_cast<uint4*>(og + 8) = make_uint4(pk[8], pk[9], pk[10], pk[11]);
  }
}

} // namespace

extern "C" void kernel_launch(void* const* d_in, const int* in_sizes, int n_in,
                              void* d_out, int out_size, void* d_ws, size_t ws_size,
                              hipStream_t stream) {
  const float* xr = (const float*)d_in[0];   // dict order: x_real first
  const float* xi = (const float*)d_in[1];
  unsigned* out = (unsigned*)d_out;          // dword = im(bf16) | re(bf16)<<16
  const int nbc = in_sizes[0] / 3072;        // 8192 blocks of (8*4*2*48)
  bd2af_kernel<<<nbc, 256, 0, stream>>>(xr, xi, out, nbc);
}